// Round 9
// baseline (8567.437 us; speedup 1.0000x reference)
//
#include <hip/hip_runtime.h>
#include <math.h>

// Persistent cooperative 2-layer LSTM. Round 9: layer-specialized WGs.
// B=64, T=512, D=128, H=512. 256 WGs x 256 threads (4 waves), 1 block/CU.
// WG w: half = w>>7 (0: layer0, 1: layer1); idx = w&127: bgrp = idx&1
// (32 batches), cg = idx>>1 (8 h-cols => 32 gate-rows).
// Waves: wid = tid>>6: khalf = wid&1, ntile = wid>>1 (16 gate-rows each).
//   L0 WG: K=640 ([h0(t-1); x_t]), khalf -> k 0..320 / 320..640 (10 frags).
//   L1 WG: K=1024 ([h1(t-2); h0(t-1)]), khalf -> 0..512 / 512..1024 (16 frags).
// Rationale: per-WG A(ring)-traffic = rows x K regardless of col count, so
// halving WGs-per-layer (8 cols each) halves the 50 MB/iter L3 ring traffic.
// W (bf16 hi/lo) fully in LDS: L0 82KB, L1 131KB; x-stage overlays L0's
// unused W tail. Split precision: gates = Whi*hhi + Whi*hlo + Wlo*hhi.
// All sync/coherence identical to round 8 (proven): split barrier, agent
// stores, per-iter agent-acquire fence, pipeline skew t / t-1 / t-2.
//
// ws layout (bytes): flags 256*64 @0; rel 32*64 @16384; uints @20480:
//   r0h[2][64][256], r0l, r1h, r1l (128KB each).

#define TT 512
#define NWG 256

typedef __attribute__((ext_vector_type(8))) short short8;
typedef __attribute__((ext_vector_type(4))) float f32x4;

// red[khalf][m 0..31][n 0..31 pad 35]
#define RED(K,M,N) ((((K)*32+(M))*35)+(N))
#define RED_TOT (2*32*35)

__device__ __forceinline__ float fsigmoid(float v){ return 1.f/(1.f+__expf(-v)); }
__device__ __forceinline__ float ftanh(float v){ return 2.f/(1.f+__expf(-2.f*v)) - 1.f; }

__device__ __forceinline__ unsigned short f2bf(float f){
  unsigned u = __float_as_uint(f);
  unsigned r = ((u>>16)&1u) + 0x7FFFu;
  return (unsigned short)((u + r)>>16);
}
__device__ __forceinline__ float bf2f(unsigned short s){
  return __uint_as_float(((unsigned)s)<<16);
}
__device__ __forceinline__ void cvt8(const float4& a, const float4& b,
                                     short8& hi, short8& lo){
  float v[8] = {a.x,a.y,a.z,a.w,b.x,b.y,b.z,b.w};
  #pragma unroll
  for (int i=0;i<8;i++){
    unsigned short h = f2bf(v[i]);
    unsigned short l = f2bf(v[i] - bf2f(h));
    ((unsigned short*)&hi)[i] = h;
    ((unsigned short*)&lo)[i] = l;
  }
}

__device__ __forceinline__ void st_agent_f(float* p, float v){
  __hip_atomic_store(p, v, __ATOMIC_RELAXED, __HIP_MEMORY_SCOPE_AGENT);
}
__device__ __forceinline__ void st_agent_u32(unsigned* p, unsigned v){
  __hip_atomic_store(p, v, __ATOMIC_RELAXED, __HIP_MEMORY_SCOPE_AGENT);
}

// Proven barrier topology (rounds 3-8), split into arrive/wait.
__device__ __forceinline__ void gb_arrive(unsigned* flags, int wg, int tid, unsigned phase){
  asm volatile("s_waitcnt vmcnt(0)" ::: "memory");  // ring stores complete
  __syncthreads();
  if (tid == 0)
    __hip_atomic_store(&flags[wg*16], phase, __ATOMIC_RELAXED, __HIP_MEMORY_SCOPE_AGENT);
}
__device__ __forceinline__ void gb_wait(unsigned* flags, unsigned* rel,
                                        int wg, int tid, unsigned phase){
  if (wg == 0 && tid < 64){
    for(;;){
      bool ok = true;
      #pragma unroll
      for (int i=0;i<4;i++){
        unsigned v = __hip_atomic_load(&flags[(tid*4+i)*16], __ATOMIC_RELAXED, __HIP_MEMORY_SCOPE_AGENT);
        ok &= (v >= phase);
      }
      if (__all(ok)) break;
      __builtin_amdgcn_s_sleep(2);
    }
    if (tid < 32)
      __hip_atomic_store(&rel[tid*16], phase, __ATOMIC_RELAXED, __HIP_MEMORY_SCOPE_AGENT);
  }
  if (tid == 0 && wg != 0){
    unsigned* myrel = &rel[(wg>>3)*16];
    while (__hip_atomic_load(myrel, __ATOMIC_RELAXED, __HIP_MEMORY_SCOPE_AGENT) < phase)
      __builtin_amdgcn_s_sleep(4);
  }
  __syncthreads();
  __builtin_amdgcn_fence(__ATOMIC_ACQUIRE, "agent");  // invalidate stale L1/L2
}

// Gate MFMA loop; A-frags loaded directly as short8 from packed bf16 rings
// (or the LDS x-stage on L0/khalf1). 6 MFMA per kf (split precision).
template<int KFC, int LAYER, int KHALF>
__device__ __forceinline__ void gates_mfma(
    const unsigned* __restrict__ rAh, const unsigned* __restrict__ rAl,
    const unsigned* __restrict__ rBh, const unsigned* __restrict__ rBl,
    const unsigned* xsh_t, const unsigned* xsl_t,
    const unsigned short* wh, const unsigned short* wlo,
    int m0, int m1, int kslot, int nidx,
    f32x4& acc0, f32x4& acc1)
{
  constexpr int KB = LAYER ? (KHALF*512) : (KHALF*320);
  #pragma unroll
  for (int kf=0; kf<KFC; ++kf){
    short8 a0h,a0l,a1h,a1l;
    if (LAYER==0 && KHALF==1 && kf>=6){
      int d2 = (kf-6)*16 + kslot*4;          // uint offset within x row
      a0h = *(const short8*)(xsh_t + (m0&31)*68 + d2);
      a0l = *(const short8*)(xsl_t + (m0&31)*68 + d2);
      a1h = *(const short8*)(xsh_t + (m1&31)*68 + d2);
      a1l = *(const short8*)(xsl_t + (m1&31)*68 + d2);
    } else {
      int kk = KB + kf*32 + kslot*8;
      const unsigned *bh, *bl; int k2;
      if (LAYER==1 && KHALF==1){ bh = rBh; bl = rBl; k2 = (kk-512)>>1; }
      else                     { bh = rAh; bl = rAl; k2 = kk>>1;       }
      a0h = *(const short8*)(bh + m0*256 + k2);
      a0l = *(const short8*)(bl + m0*256 + k2);
      a1h = *(const short8*)(bh + m1*256 + k2);
      a1l = *(const short8*)(bl + m1*256 + k2);
    }
    int c = ((KHALF*KFC + kf)*4 + kslot)*32 + nidx;
    short8 bhW = *(const short8*)(wh  + (size_t)c*8);
    short8 blW = *(const short8*)(wlo + (size_t)c*8);
    acc0 = __builtin_amdgcn_mfma_f32_16x16x32_bf16(a0h, bhW, acc0, 0,0,0);
    acc0 = __builtin_amdgcn_mfma_f32_16x16x32_bf16(a0l, bhW, acc0, 0,0,0);
    acc0 = __builtin_amdgcn_mfma_f32_16x16x32_bf16(a0h, blW, acc0, 0,0,0);
    acc1 = __builtin_amdgcn_mfma_f32_16x16x32_bf16(a1h, bhW, acc1, 0,0,0);
    acc1 = __builtin_amdgcn_mfma_f32_16x16x32_bf16(a1l, bhW, acc1, 0,0,0);
    acc1 = __builtin_amdgcn_mfma_f32_16x16x32_bf16(a1h, blW, acc1, 0,0,0);
  }
}

__global__ __launch_bounds__(256, 1) void lstm_pers(
    const float* __restrict__ x,    const float* __restrict__ h0in, const float* __restrict__ c0in,
    const float* __restrict__ wih0, const float* __restrict__ whh0,
    const float* __restrict__ bih0, const float* __restrict__ bhh0,
    const float* __restrict__ wih1, const float* __restrict__ whh1,
    const float* __restrict__ bih1, const float* __restrict__ bhh1,
    const float* __restrict__ wlin, const float* __restrict__ blin,
    float* __restrict__ out, float* ws)
{
  // L1 WG: W uses all 32768 chunks*? elems; L0 WG: W uses [0,20480) ushorts,
  // x-stage overlays the tail at +20480 (8704 ushorts) of each plane.
  __shared__ __align__(16) unsigned short wlds_hi[32768];   // 65,536 B
  __shared__ __align__(16) unsigned short wlds_lo[32768];   // 65,536 B
  __shared__ __align__(16) float red[RED_TOT];              //  8,960 B
  const int tid = threadIdx.x, wg = blockIdx.x;
  const int lane = tid & 63;
  const int wid  = tid >> 6;
  const int half = wg >> 7;            // 0: layer0 WG, 1: layer1 WG
  const int idx  = wg & 127;
  const int bgrp = idx & 1;
  const int cg   = idx >> 1;           // 0..63
  const int colbase = cg*8;
  const int khalf = wid & 1;
  const int ntile = wid >> 1;

  unsigned* flags = (unsigned*)ws;                  // 256 x 64B lines
  unsigned* rel   = ((unsigned*)ws) + 4096;         // 32 x 64B lines @16384
  unsigned* r0h = ((unsigned*)ws) + 5120;           // [2][64][256] each
  unsigned* r0l = r0h + 32768;
  unsigned* r1h = r0h + 65536;
  unsigned* r1l = r0h + 98304;

  unsigned* xsh_s = (unsigned*)(wlds_hi + 20480);   // L0 WGs only (overlay)
  unsigned* xsl_s = (unsigned*)(wlds_lo + 20480);

  // ---- W (bf16 hi/lo) into LDS, once. chunk c = ((kh*KFC+kf)*4+ks)*32+n ----
  if (half == 0){
    for (int c = tid; c < 2560; c += 256){
      int kh = c / 1280; int rem = c - kh*1280;
      int kf = rem >> 7; int rem2 = rem & 127;
      int ks = rem2 >> 5; int n = rem2 & 31;
      int kk = kh*320 + kf*32 + ks*8;
      int wrow = (n>>3)*512 + colbase + (n&7);
      const float* src; long off;
      if (kk < 512){ src = whh0; off = (long)wrow*512 + kk; }
      else         { src = wih0; off = (long)wrow*128 + (kk-512); }
      float4 a = *(const float4*)(src + off);
      float4 b = *(const float4*)(src + off + 4);
      short8 hi, lo; cvt8(a, b, hi, lo);
      *(short8*)(wlds_hi + (size_t)c*8) = hi;
      *(short8*)(wlds_lo + (size_t)c*8) = lo;
    }
  } else {
    for (int c = tid; c < 4096; c += 256){
      int kh = c >> 11; int rem = c & 2047;
      int kf = rem >> 7; int rem2 = rem & 127;
      int ks = rem2 >> 5; int n = rem2 & 31;
      int kk = kh*512 + kf*32 + ks*8;
      int wrow = (n>>3)*512 + colbase + (n&7);
      const float* src; long off;
      if (kk < 512){ src = whh1; off = (long)wrow*512 + kk; }
      else         { src = wih1; off = (long)wrow*512 + (kk-512); }
      float4 a = *(const float4*)(src + off);
      float4 b = *(const float4*)(src + off + 4);
      short8 hi, lo; cvt8(a, b, hi, lo);
      *(short8*)(wlds_hi + (size_t)c*8) = hi;
      *(short8*)(wlds_lo + (size_t)c*8) = lo;
    }
  }

  // ---- activation-role state: 1 cell/thread, this WG's layer ----
  const int m_l = tid >> 3;            // 0..31 local batch
  const int cl  = tid & 7;             // 0..7 local col
  const int col_own = colbase + cl;
  const int bb_a = bgrp*32 + m_l;
  float biasr[4], cst;
  #pragma unroll
  for (int g=0; g<4; ++g){
    biasr[g] = half ? (bih1[g*512+col_own] + bhh1[g*512+col_own])
                    : (bih0[g*512+col_own] + bhh0[g*512+col_own]);
  }
  cst = c0in[half*32768 + bb_a*512 + col_own];
  float blin_r = blin[0];

  // ---- y-role state: lane holds wlin[8k..8k+8) ----
  float wl[8];
  {
    const float4* wp = (const float4*)wlin + (lane*2);
    float4 w0 = wp[0], w1 = wp[1];
    wl[0]=w0.x; wl[1]=w0.y; wl[2]=w0.z; wl[3]=w0.w;
    wl[4]=w1.x; wl[5]=w1.y; wl[6]=w1.z; wl[7]=w1.w;
  }

  // ---- init h rings (slot 1) packed bf16 hi/lo, 32-bit agent stores ----
  {
    int gidx = wg*256 + tid;             // [0, 65536)
    if (!(gidx & 1)){
      float v0 = h0in[gidx], v1 = h0in[gidx+1];
      unsigned short hA = f2bf(v0), lA = f2bf(v0 - bf2f(hA));
      unsigned short hB = f2bf(v1), lB = f2bf(v1 - bf2f(hB));
      unsigned uh = (unsigned)hA | ((unsigned)hB<<16);
      unsigned ul = (unsigned)lA | ((unsigned)lB<<16);
      int hf2 = gidx >> 15;
      int id2 = (gidx & 32767) >> 1;
      unsigned* ph = hf2 ? r1h : r0h;
      unsigned* pl = hf2 ? r1l : r0l;
      st_agent_u32(ph + 16384 + id2, uh);
      st_agent_u32(pl + 16384 + id2, ul);
    }
  }

  // ---- x stage for t=0 (L0 WGs) ----
  if (half == 0){
    int m = tid>>3, dd = (tid&7)*16;
    const float* xp = x + ((size_t)(bgrp*32+m))*65536 + 0*128 + dd;
    float4 v0 = *(const float4*)xp,      v1 = *(const float4*)(xp+4),
           v2 = *(const float4*)(xp+8),  v3 = *(const float4*)(xp+12);
    float vv[16] = {v0.x,v0.y,v0.z,v0.w, v1.x,v1.y,v1.z,v1.w,
                    v2.x,v2.y,v2.z,v2.w, v3.x,v3.y,v3.z,v3.w};
    unsigned uh[8], ul[8];
    #pragma unroll
    for (int j=0;j<8;j++){
      unsigned short hA = f2bf(vv[2*j]),   hB = f2bf(vv[2*j+1]);
      unsigned short lA = f2bf(vv[2*j]-bf2f(hA)), lB = f2bf(vv[2*j+1]-bf2f(hB));
      uh[j] = (unsigned)hA | ((unsigned)hB<<16);
      ul[j] = (unsigned)lA | ((unsigned)lB<<16);
    }
    unsigned* dh = xsh_s + m*68 + (dd>>1);
    unsigned* dl = xsl_s + m*68 + (dd>>1);
    *(uint4*)dh     = make_uint4(uh[0],uh[1],uh[2],uh[3]);
    *(uint4*)(dh+4) = make_uint4(uh[4],uh[5],uh[6],uh[7]);
    *(uint4*)dl     = make_uint4(ul[0],ul[1],ul[2],ul[3]);
    *(uint4*)(dl+4) = make_uint4(ul[4],ul[5],ul[6],ul[7]);
  }

  unsigned phase = 1;
  gb_arrive(flags, wg, tid, phase);
  gb_wait(flags, rel, wg, tid, phase);
  ++phase;

  const int m0 = bgrp*32 + (lane & 15);
  const int m1 = m0 + 16;
  const int kslot = lane >> 4;
  const int nidx  = ntile*16 + (lane & 15);

  for (int t = 0; t <= TT+1; ++t){
    const bool act = half ? (t >= 1 && t <= TT) : (t < TT);

    // ---- gates (MFMA) ----
    if (act){
      const unsigned *rAh,*rAl,*rBh,*rBl;
      if (half == 0){
        int s = ((t+1)&1)*16384;          // h0(t-1)
        rAh = r0h+s; rAl = r0l+s; rBh = 0; rBl = 0;
      } else {
        int sA = (t&1)*16384;             // h1(t-2)
        int sB = ((t+1)&1)*16384;         // h0(t-1)
        rAh = r1h+sA; rAl = r1l+sA; rBh = r0h+sB; rBl = r0l+sB;
      }
      const unsigned* xsh_t = xsh_s + (t&1)*2176;
      const unsigned* xsl_t = xsl_s + (t&1)*2176;
      f32x4 acc0 = {0.f,0.f,0.f,0.f}, acc1 = {0.f,0.f,0.f,0.f};
      if (half == 0){
        if (khalf == 0) gates_mfma<10,0,0>(rAh,rAl,rBh,rBl,xsh_t,xsl_t,wlds_hi,wlds_lo,m0,m1,kslot,nidx,acc0,acc1);
        else            gates_mfma<10,0,1>(rAh,rAl,rBh,rBl,xsh_t,xsl_t,wlds_hi,wlds_lo,m0,m1,kslot,nidx,acc0,acc1);
      } else {
        if (khalf == 0) gates_mfma<16,1,0>(rAh,rAl,rBh,rBl,xsh_t,xsl_t,wlds_hi,wlds_lo,m0,m1,kslot,nidx,acc0,acc1);
        else            gates_mfma<16,1,1>(rAh,rAl,rBh,rBl,xsh_t,xsl_t,wlds_hi,wlds_lo,m0,m1,kslot,nidx,acc0,acc1);
      }
      // D layout (m89): col n = lane&15, row = (lane>>4)*4+r.
      #pragma unroll
      for (int r=0; r<4; ++r){
        int mm = kslot*4 + r;
        red[RED(khalf, mm,    nidx)] = acc0[r];
        red[RED(khalf, 16+mm, nidx)] = acc1[r];
      }
    }
    __syncthreads();

    // ---- activation: one cell per thread; pair-pack ring writes ----
    {
      float h = 0.f;
      if (act){
        float g4[4];
        #pragma unroll
        for (int g=0; g<4; ++g){
          int n = g*8 + cl;
          g4[g] = red[RED(0,m_l,n)] + red[RED(1,m_l,n)] + biasr[g];
        }
        float gi = fsigmoid(g4[0]);
        float gf = fsigmoid(g4[1]);
        float gg = ftanh   (g4[2]);
        float go = fsigmoid(g4[3]);
        float c = gf*cst + gi*gg;
        cst = c;
        h = go * ftanh(c);
      }
      float h_oth = __shfl_xor(h, 1, 64);
      if (act && !(tid & 1)){
        unsigned short hA = f2bf(h),     lA = f2bf(h - bf2f(hA));
        unsigned short hB = f2bf(h_oth), lB = f2bf(h_oth - bf2f(hB));
        unsigned uh = (unsigned)hA | ((unsigned)hB<<16);
        unsigned ul = (unsigned)lA | ((unsigned)lB<<16);
        int slot = half ? ((t+1)&1) : (t&1);
        int off = slot*16384 + bb_a*256 + (col_own>>1);
        if (half){ st_agent_u32(r1h + off, uh); st_agent_u32(r1l + off, ul); }
        else     { st_agent_u32(r0h + off, uh); st_agent_u32(r0l + off, ul); }
      }
    }

    gb_arrive(flags, wg, tid, phase);

    // ==== overlap region: only old-slot / pure-input reads ====
    if (t >= 2 && half == 1 && idx < 64 && wid == 0){   // y(t-2): 64 WGs x 1 batch
      int sy = t - 2;
      int yb = idx;
      const uint4* qh = (const uint4*)(r1h + (t&1)*16384 + yb*256) + lane;
      const uint4* ql = (const uint4*)(r1l + (t&1)*16384 + yb*256) + lane;
      uint4 a = qh[0], b = ql[0];
      float p = 0.f;
      {
        unsigned qa, qb; float e0, e1;
        qa=a.x; qb=b.x;
        e0 = __uint_as_float(qa<<16) + __uint_as_float(qb<<16);
        e1 = __uint_as_float(qa & 0xFFFF0000u) + __uint_as_float(qb & 0xFFFF0000u);
        p += e0*wl[0] + e1*wl[1];
        qa=a.y; qb=b.y;
        e0 = __uint_as_float(qa<<16) + __uint_as_float(qb<<16);
        e1 = __uint_as_float(qa & 0xFFFF0000u) + __uint_as_float(qb & 0xFFFF0000u);
        p += e0*wl[2] + e1*wl[3];
        qa=a.z; qb=b.z;
        e0 = __uint_as_float(qa<<16) + __uint_as_float(qb<<16);
        e1 = __uint_as_float(qa & 0xFFFF0000u) + __uint_as_float(qb & 0xFFFF0000u);
        p += e0*wl[4] + e1*wl[5];
        qa=a.w; qb=b.w;
        e0 = __uint_as_float(qa<<16) + __uint_as_float(qb<<16);
        e1 = __uint_as_float(qa & 0xFFFF0000u) + __uint_as_float(qb & 0xFFFF0000u);
        p += e0*wl[6] + e1*wl[7];
      }
      #pragma unroll
      for (int m=1; m<64; m<<=1) p += __shfl_xor(p, m, 64);
      if (lane == 0) st_agent_f(&out[yb*512 + sy], p + blin_r);
    }
    if (half == 0 && t+1 < TT){          // stage x(t+1) into LDS buf (t+1)&1
      int m = tid>>3, dd = (tid&7)*16;
      const float* xp = x + ((size_t)(bgrp*32+m))*65536 + (size_t)(t+1)*128 + dd;
      float4 v0 = *(const float4*)xp,      v1 = *(const float4*)(xp+4),
             v2 = *(const float4*)(xp+8),  v3 = *(const float4*)(xp+12);
      float vv[16] = {v0.x,v0.y,v0.z,v0.w, v1.x,v1.y,v1.z,v1.w,
                      v2.x,v2.y,v2.z,v2.w, v3.x,v3.y,v3.z,v3.w};
      unsigned uh[8], ul[8];
      #pragma unroll
      for (int j=0;j<8;j++){
        unsigned short hA = f2bf(vv[2*j]),   hB = f2bf(vv[2*j+1]);
        unsigned short lA = f2bf(vv[2*j]-bf2f(hA)), lB = f2bf(vv[2*j+1]-bf2f(hB));
        uh[j] = (unsigned)hA | ((unsigned)hB<<16);
        ul[j] = (unsigned)lA | ((unsigned)lB<<16);
      }
      unsigned* dh = xsh_s + ((t+1)&1)*2176 + m*68 + (dd>>1);
      unsigned* dl = xsl_s + ((t+1)&1)*2176 + m*68 + (dd>>1);
      *(uint4*)dh     = make_uint4(uh[0],uh[1],uh[2],uh[3]);
      *(uint4*)(dh+4) = make_uint4(uh[4],uh[5],uh[6],uh[7]);
      *(uint4*)dl     = make_uint4(ul[0],ul[1],ul[2],ul[3]);
      *(uint4*)(dl+4) = make_uint4(ul[4],ul[5],ul[6],ul[7]);
    }
    // ==== end overlap ====

    gb_wait(flags, rel, wg, tid, phase);
    ++phase;
  }
}

extern "C" void kernel_launch(void* const* d_in, const int* in_sizes, int n_in,
                              void* d_out, int out_size, void* d_ws, size_t ws_size,
                              hipStream_t stream)
{
  (void)in_sizes; (void)n_in; (void)out_size; (void)ws_size;
  const float* x    = (const float*)d_in[0];
  const float* h0   = (const float*)d_in[1];
  const float* c0   = (const float*)d_in[2];
  const float* wih0 = (const float*)d_in[3];
  const float* whh0 = (const float*)d_in[4];
  const float* bih0 = (const float*)d_in[5];
  const float* bhh0 = (const float*)d_in[6];
  const float* wih1 = (const float*)d_in[7];
  const float* whh1 = (const float*)d_in[8];
  const float* bih1 = (const float*)d_in[9];
  const float* bhh1 = (const float*)d_in[10];
  const float* wlin = (const float*)d_in[11];
  const float* blin = (const float*)d_in[12];
  float* outp = (float*)d_out;
  float* wsp  = (float*)d_ws;

  // zero flags (16KB) + release lines (2KB); rings fully rewritten by the kernel
  hipMemsetAsync(d_ws, 0, 18432, stream);

  void* args[] = { &x, &h0, &c0, &wih0, &whh0, &bih0, &bhh0,
                   &wih1, &whh1, &bih1, &bhh1, &wlin, &blin, &outp, &wsp };
  hipError_t err = hipLaunchCooperativeKernel((const void*)lstm_pers,
                                              dim3(NWG), dim3(256), args, 0, stream);
  if (err != hipSuccess){
    // Fallback: 1 block/CU (140KB LDS), 256 blocks on 256 CUs -> co-resident.
    hipLaunchKernelGGL(lstm_pers, dim3(NWG), dim3(256), 0, stream,
                       x, h0, c0, wih0, whh0, bih0, bhh0,
                       wih1, whh1, bih1, bhh1, wlin, blin, outp, wsp);
  }
}

// Round 10
// 8385.188 us; speedup vs baseline: 1.0217x; 1.0217x over previous
//
#include <hip/hip_runtime.h>
#include <math.h>

// Persistent cooperative 2-layer LSTM. Round 10: NO per-iteration L2
// invalidate. Ring reads are 64-bit relaxed AGENT-scope atomic loads (served
// coherently at L3, bypassing L1/L2), so the agent-acquire fence (buffer_inv,
// the suspected 8-10us/iter cost) is removed. x stays plain-cached (pure
// input, immutable => L2 copies always valid, and now they survive).
// Everything else identical to round 9 (layer-specialized WGs).
//
// B=64, T=512, D=128, H=512. 256 WGs x 256 threads (4 waves), 1 block/CU.
// WG w: half = w>>7 (0: layer0, 1: layer1); idx = w&127: bgrp = idx&1,
// cg = idx>>1 (8 h-cols => 32 gate-rows).
// Waves: wid = tid>>6: khalf = wid&1, ntile = wid>>1.
// Split precision: gates = Whi*hhi + Whi*hlo + Wlo*hhi (fp32 accum, ~2^-17).
// Pipeline: iter t = L0 step t, L1 step t-1, y step t-2; one barrier/iter
// (proven topology: per-WG flag lines + WG0 aggregate + 32 release lines;
// producer vmcnt(0) before flag => flag@L3 implies data@L3).
//
// ws layout (bytes): flags 256*64 @0; rel 32*64 @16384; uints @20480:
//   r0h[2][64][256], r0l, r1h, r1l (128KB each).

#define TT 512
#define NWG 256

typedef __attribute__((ext_vector_type(8))) short short8;
typedef __attribute__((ext_vector_type(4))) float f32x4;

// red[khalf][m 0..31][n 0..31 pad 35]
#define RED(K,M,N) ((((K)*32+(M))*35)+(N))
#define RED_TOT (2*32*35)

__device__ __forceinline__ float fsigmoid(float v){ return 1.f/(1.f+__expf(-v)); }
__device__ __forceinline__ float ftanh(float v){ return 2.f/(1.f+__expf(-2.f*v)) - 1.f; }

__device__ __forceinline__ unsigned short f2bf(float f){
  unsigned u = __float_as_uint(f);
  unsigned r = ((u>>16)&1u) + 0x7FFFu;
  return (unsigned short)((u + r)>>16);
}
__device__ __forceinline__ float bf2f(unsigned short s){
  return __uint_as_float(((unsigned)s)<<16);
}
__device__ __forceinline__ void cvt8(const float4& a, const float4& b,
                                     short8& hi, short8& lo){
  float v[8] = {a.x,a.y,a.z,a.w,b.x,b.y,b.z,b.w};
  #pragma unroll
  for (int i=0;i<8;i++){
    unsigned short h = f2bf(v[i]);
    unsigned short l = f2bf(v[i] - bf2f(h));
    ((unsigned short*)&hi)[i] = h;
    ((unsigned short*)&lo)[i] = l;
  }
}

__device__ __forceinline__ void st_agent_f(float* p, float v){
  __hip_atomic_store(p, v, __ATOMIC_RELAXED, __HIP_MEMORY_SCOPE_AGENT);
}
__device__ __forceinline__ void st_agent_u32(unsigned* p, unsigned v){
  __hip_atomic_store(p, v, __ATOMIC_RELAXED, __HIP_MEMORY_SCOPE_AGENT);
}

// Coherent 16B ring read: two 64-bit relaxed agent atomic loads (L3-served).
__device__ __forceinline__ short8 ld_ring16(const unsigned* p){
  const unsigned long long* q = (const unsigned long long*)p;
  union { unsigned long long u[2]; short8 s; } v;
  v.u[0] = __hip_atomic_load(&q[0], __ATOMIC_RELAXED, __HIP_MEMORY_SCOPE_AGENT);
  v.u[1] = __hip_atomic_load(&q[1], __ATOMIC_RELAXED, __HIP_MEMORY_SCOPE_AGENT);
  return v.s;
}
__device__ __forceinline__ void ld_ring16_u(const unsigned* p, unsigned o[4]){
  const unsigned long long* q = (const unsigned long long*)p;
  unsigned long long a = __hip_atomic_load(&q[0], __ATOMIC_RELAXED, __HIP_MEMORY_SCOPE_AGENT);
  unsigned long long b = __hip_atomic_load(&q[1], __ATOMIC_RELAXED, __HIP_MEMORY_SCOPE_AGENT);
  o[0] = (unsigned)a; o[1] = (unsigned)(a>>32);
  o[2] = (unsigned)b; o[3] = (unsigned)(b>>32);
}

// Barrier (rounds 3-9 topology), split arrive/wait. NO acquire fence:
// readers use agent-scope atomic loads instead (per-access coherence).
__device__ __forceinline__ void gb_arrive(unsigned* flags, int wg, int tid, unsigned phase){
  asm volatile("s_waitcnt vmcnt(0)" ::: "memory");  // ring stores complete @L3
  __syncthreads();
  if (tid == 0)
    __hip_atomic_store(&flags[wg*16], phase, __ATOMIC_RELAXED, __HIP_MEMORY_SCOPE_AGENT);
}
__device__ __forceinline__ void gb_wait(unsigned* flags, unsigned* rel,
                                        int wg, int tid, unsigned phase){
  if (wg == 0 && tid < 64){
    for(;;){
      bool ok = true;
      #pragma unroll
      for (int i=0;i<4;i++){
        unsigned v = __hip_atomic_load(&flags[(tid*4+i)*16], __ATOMIC_RELAXED, __HIP_MEMORY_SCOPE_AGENT);
        ok &= (v >= phase);
      }
      if (__all(ok)) break;
      __builtin_amdgcn_s_sleep(2);
    }
    if (tid < 32)
      __hip_atomic_store(&rel[tid*16], phase, __ATOMIC_RELAXED, __HIP_MEMORY_SCOPE_AGENT);
  }
  if (tid == 0 && wg != 0){
    unsigned* myrel = &rel[(wg>>3)*16];
    while (__hip_atomic_load(myrel, __ATOMIC_RELAXED, __HIP_MEMORY_SCOPE_AGENT) < phase)
      __builtin_amdgcn_s_sleep(4);
  }
  __syncthreads();
  asm volatile("" ::: "memory");   // compiler barrier only (no HW invalidate)
}

// Gate MFMA loop; ring A-frags via agent atomic loads, x via LDS stage.
template<int KFC, int LAYER, int KHALF>
__device__ __forceinline__ void gates_mfma(
    const unsigned* __restrict__ rAh, const unsigned* __restrict__ rAl,
    const unsigned* __restrict__ rBh, const unsigned* __restrict__ rBl,
    const unsigned* xsh_t, const unsigned* xsl_t,
    const unsigned short* wh, const unsigned short* wlo,
    int m0, int m1, int kslot, int nidx,
    f32x4& acc0, f32x4& acc1)
{
  constexpr int KB = LAYER ? (KHALF*512) : (KHALF*320);
  #pragma unroll
  for (int kf=0; kf<KFC; ++kf){
    short8 a0h,a0l,a1h,a1l;
    if (LAYER==0 && KHALF==1 && kf>=6){
      int d2 = (kf-6)*16 + kslot*4;          // uint offset within x row
      a0h = *(const short8*)(xsh_t + (m0&31)*68 + d2);
      a0l = *(const short8*)(xsl_t + (m0&31)*68 + d2);
      a1h = *(const short8*)(xsh_t + (m1&31)*68 + d2);
      a1l = *(const short8*)(xsl_t + (m1&31)*68 + d2);
    } else {
      int kk = KB + kf*32 + kslot*8;
      const unsigned *bh, *bl; int k2;
      if (LAYER==1 && KHALF==1){ bh = rBh; bl = rBl; k2 = (kk-512)>>1; }
      else                     { bh = rAh; bl = rAl; k2 = kk>>1;       }
      a0h = ld_ring16(bh + m0*256 + k2);
      a0l = ld_ring16(bl + m0*256 + k2);
      a1h = ld_ring16(bh + m1*256 + k2);
      a1l = ld_ring16(bl + m1*256 + k2);
    }
    int c = ((KHALF*KFC + kf)*4 + kslot)*32 + nidx;
    short8 bhW = *(const short8*)(wh  + (size_t)c*8);
    short8 blW = *(const short8*)(wlo + (size_t)c*8);
    acc0 = __builtin_amdgcn_mfma_f32_16x16x32_bf16(a0h, bhW, acc0, 0,0,0);
    acc0 = __builtin_amdgcn_mfma_f32_16x16x32_bf16(a0l, bhW, acc0, 0,0,0);
    acc0 = __builtin_amdgcn_mfma_f32_16x16x32_bf16(a0h, blW, acc0, 0,0,0);
    acc1 = __builtin_amdgcn_mfma_f32_16x16x32_bf16(a1h, bhW, acc1, 0,0,0);
    acc1 = __builtin_amdgcn_mfma_f32_16x16x32_bf16(a1l, bhW, acc1, 0,0,0);
    acc1 = __builtin_amdgcn_mfma_f32_16x16x32_bf16(a1h, blW, acc1, 0,0,0);
  }
}

__global__ __launch_bounds__(256, 1) void lstm_pers(
    const float* __restrict__ x,    const float* __restrict__ h0in, const float* __restrict__ c0in,
    const float* __restrict__ wih0, const float* __restrict__ whh0,
    const float* __restrict__ bih0, const float* __restrict__ bhh0,
    const float* __restrict__ wih1, const float* __restrict__ whh1,
    const float* __restrict__ bih1, const float* __restrict__ bhh1,
    const float* __restrict__ wlin, const float* __restrict__ blin,
    float* __restrict__ out, float* ws)
{
  __shared__ __align__(16) unsigned short wlds_hi[32768];   // 65,536 B
  __shared__ __align__(16) unsigned short wlds_lo[32768];   // 65,536 B
  __shared__ __align__(16) float red[RED_TOT];              //  8,960 B
  const int tid = threadIdx.x, wg = blockIdx.x;
  const int lane = tid & 63;
  const int wid  = tid >> 6;
  const int half = wg >> 7;            // 0: layer0 WG, 1: layer1 WG
  const int idx  = wg & 127;
  const int bgrp = idx & 1;
  const int cg   = idx >> 1;           // 0..63
  const int colbase = cg*8;
  const int khalf = wid & 1;
  const int ntile = wid >> 1;

  unsigned* flags = (unsigned*)ws;                  // 256 x 64B lines
  unsigned* rel   = ((unsigned*)ws) + 4096;         // 32 x 64B lines @16384
  unsigned* r0h = ((unsigned*)ws) + 5120;           // [2][64][256] each
  unsigned* r0l = r0h + 32768;
  unsigned* r1h = r0h + 65536;
  unsigned* r1l = r0h + 98304;

  unsigned* xsh_s = (unsigned*)(wlds_hi + 20480);   // L0 WGs only (overlay)
  unsigned* xsl_s = (unsigned*)(wlds_lo + 20480);

  // ---- W (bf16 hi/lo) into LDS, once. chunk c = ((kh*KFC+kf)*4+ks)*32+n ----
  if (half == 0){
    for (int c = tid; c < 2560; c += 256){
      int kh = c / 1280; int rem = c - kh*1280;
      int kf = rem >> 7; int rem2 = rem & 127;
      int ks = rem2 >> 5; int n = rem2 & 31;
      int kk = kh*320 + kf*32 + ks*8;
      int wrow = (n>>3)*512 + colbase + (n&7);
      const float* src; long off;
      if (kk < 512){ src = whh0; off = (long)wrow*512 + kk; }
      else         { src = wih0; off = (long)wrow*128 + (kk-512); }
      float4 a = *(const float4*)(src + off);
      float4 b = *(const float4*)(src + off + 4);
      short8 hi, lo; cvt8(a, b, hi, lo);
      *(short8*)(wlds_hi + (size_t)c*8) = hi;
      *(short8*)(wlds_lo + (size_t)c*8) = lo;
    }
  } else {
    for (int c = tid; c < 4096; c += 256){
      int kh = c >> 11; int rem = c & 2047;
      int kf = rem >> 7; int rem2 = rem & 127;
      int ks = rem2 >> 5; int n = rem2 & 31;
      int kk = kh*512 + kf*32 + ks*8;
      int wrow = (n>>3)*512 + colbase + (n&7);
      const float* src; long off;
      if (kk < 512){ src = whh1; off = (long)wrow*512 + kk; }
      else         { src = wih1; off = (long)wrow*512 + (kk-512); }
      float4 a = *(const float4*)(src + off);
      float4 b = *(const float4*)(src + off + 4);
      short8 hi, lo; cvt8(a, b, hi, lo);
      *(short8*)(wlds_hi + (size_t)c*8) = hi;
      *(short8*)(wlds_lo + (size_t)c*8) = lo;
    }
  }

  // ---- activation-role state: 1 cell/thread, this WG's layer ----
  const int m_l = tid >> 3;            // 0..31 local batch
  const int cl  = tid & 7;             // 0..7 local col
  const int col_own = colbase + cl;
  const int bb_a = bgrp*32 + m_l;
  float biasr[4], cst;
  #pragma unroll
  for (int g=0; g<4; ++g){
    biasr[g] = half ? (bih1[g*512+col_own] + bhh1[g*512+col_own])
                    : (bih0[g*512+col_own] + bhh0[g*512+col_own]);
  }
  cst = c0in[half*32768 + bb_a*512 + col_own];
  float blin_r = blin[0];

  // ---- y-role state: lane holds wlin[8k..8k+8) ----
  float wl[8];
  {
    const float4* wp = (const float4*)wlin + (lane*2);
    float4 w0 = wp[0], w1 = wp[1];
    wl[0]=w0.x; wl[1]=w0.y; wl[2]=w0.z; wl[3]=w0.w;
    wl[4]=w1.x; wl[5]=w1.y; wl[6]=w1.z; wl[7]=w1.w;
  }

  // ---- init h rings (slot 1) packed bf16 hi/lo, 32-bit agent stores ----
  {
    int gidx = wg*256 + tid;             // [0, 65536)
    if (!(gidx & 1)){
      float v0 = h0in[gidx], v1 = h0in[gidx+1];
      unsigned short hA = f2bf(v0), lA = f2bf(v0 - bf2f(hA));
      unsigned short hB = f2bf(v1), lB = f2bf(v1 - bf2f(hB));
      unsigned uh = (unsigned)hA | ((unsigned)hB<<16);
      unsigned ul = (unsigned)lA | ((unsigned)lB<<16);
      int hf2 = gidx >> 15;
      int id2 = (gidx & 32767) >> 1;
      unsigned* ph = hf2 ? r1h : r0h;
      unsigned* pl = hf2 ? r1l : r0l;
      st_agent_u32(ph + 16384 + id2, uh);
      st_agent_u32(pl + 16384 + id2, ul);
    }
  }

  // ---- x stage for t=0 (L0 WGs) ----
  if (half == 0){
    int m = tid>>3, dd = (tid&7)*16;
    const float* xp = x + ((size_t)(bgrp*32+m))*65536 + 0*128 + dd;
    float4 v0 = *(const float4*)xp,      v1 = *(const float4*)(xp+4),
           v2 = *(const float4*)(xp+8),  v3 = *(const float4*)(xp+12);
    float vv[16] = {v0.x,v0.y,v0.z,v0.w, v1.x,v1.y,v1.z,v1.w,
                    v2.x,v2.y,v2.z,v2.w, v3.x,v3.y,v3.z,v3.w};
    unsigned uh[8], ul[8];
    #pragma unroll
    for (int j=0;j<8;j++){
      unsigned short hA = f2bf(vv[2*j]),   hB = f2bf(vv[2*j+1]);
      unsigned short lA = f2bf(vv[2*j]-bf2f(hA)), lB = f2bf(vv[2*j+1]-bf2f(hB));
      uh[j] = (unsigned)hA | ((unsigned)hB<<16);
      ul[j] = (unsigned)lA | ((unsigned)lB<<16);
    }
    unsigned* dh = xsh_s + m*68 + (dd>>1);
    unsigned* dl = xsl_s + m*68 + (dd>>1);
    *(uint4*)dh     = make_uint4(uh[0],uh[1],uh[2],uh[3]);
    *(uint4*)(dh+4) = make_uint4(uh[4],uh[5],uh[6],uh[7]);
    *(uint4*)dl     = make_uint4(ul[0],ul[1],ul[2],ul[3]);
    *(uint4*)(dl+4) = make_uint4(ul[4],ul[5],ul[6],ul[7]);
  }

  unsigned phase = 1;
  gb_arrive(flags, wg, tid, phase);
  gb_wait(flags, rel, wg, tid, phase);
  ++phase;

  const int m0 = bgrp*32 + (lane & 15);
  const int m1 = m0 + 16;
  const int kslot = lane >> 4;
  const int nidx  = ntile*16 + (lane & 15);

  for (int t = 0; t <= TT+1; ++t){
    const bool act = half ? (t >= 1 && t <= TT) : (t < TT);

    // ---- gates (MFMA) ----
    if (act){
      const unsigned *rAh,*rAl,*rBh,*rBl;
      if (half == 0){
        int s = ((t+1)&1)*16384;          // h0(t-1)
        rAh = r0h+s; rAl = r0l+s; rBh = 0; rBl = 0;
      } else {
        int sA = (t&1)*16384;             // h1(t-2)
        int sB = ((t+1)&1)*16384;         // h0(t-1)
        rAh = r1h+sA; rAl = r1l+sA; rBh = r0h+sB; rBl = r0l+sB;
      }
      const unsigned* xsh_t = xsh_s + (t&1)*2176;
      const unsigned* xsl_t = xsl_s + (t&1)*2176;
      f32x4 acc0 = {0.f,0.f,0.f,0.f}, acc1 = {0.f,0.f,0.f,0.f};
      if (half == 0){
        if (khalf == 0) gates_mfma<10,0,0>(rAh,rAl,rBh,rBl,xsh_t,xsl_t,wlds_hi,wlds_lo,m0,m1,kslot,nidx,acc0,acc1);
        else            gates_mfma<10,0,1>(rAh,rAl,rBh,rBl,xsh_t,xsl_t,wlds_hi,wlds_lo,m0,m1,kslot,nidx,acc0,acc1);
      } else {
        if (khalf == 0) gates_mfma<16,1,0>(rAh,rAl,rBh,rBl,xsh_t,xsl_t,wlds_hi,wlds_lo,m0,m1,kslot,nidx,acc0,acc1);
        else            gates_mfma<16,1,1>(rAh,rAl,rBh,rBl,xsh_t,xsl_t,wlds_hi,wlds_lo,m0,m1,kslot,nidx,acc0,acc1);
      }
      // D layout (m89): col n = lane&15, row = (lane>>4)*4+r.
      #pragma unroll
      for (int r=0; r<4; ++r){
        int mm = kslot*4 + r;
        red[RED(khalf, mm,    nidx)] = acc0[r];
        red[RED(khalf, 16+mm, nidx)] = acc1[r];
      }
    }
    __syncthreads();

    // ---- activation: one cell per thread; pair-pack ring writes ----
    {
      float h = 0.f;
      if (act){
        float g4[4];
        #pragma unroll
        for (int g=0; g<4; ++g){
          int n = g*8 + cl;
          g4[g] = red[RED(0,m_l,n)] + red[RED(1,m_l,n)] + biasr[g];
        }
        float gi = fsigmoid(g4[0]);
        float gf = fsigmoid(g4[1]);
        float gg = ftanh   (g4[2]);
        float go = fsigmoid(g4[3]);
        float c = gf*cst + gi*gg;
        cst = c;
        h = go * ftanh(c);
      }
      float h_oth = __shfl_xor(h, 1, 64);
      if (act && !(tid & 1)){
        unsigned short hA = f2bf(h),     lA = f2bf(h - bf2f(hA));
        unsigned short hB = f2bf(h_oth), lB = f2bf(h_oth - bf2f(hB));
        unsigned uh = (unsigned)hA | ((unsigned)hB<<16);
        unsigned ul = (unsigned)lA | ((unsigned)lB<<16);
        int slot = half ? ((t+1)&1) : (t&1);
        int off = slot*16384 + bb_a*256 + (col_own>>1);
        if (half){ st_agent_u32(r1h + off, uh); st_agent_u32(r1l + off, ul); }
        else     { st_agent_u32(r0h + off, uh); st_agent_u32(r0l + off, ul); }
      }
    }

    gb_arrive(flags, wg, tid, phase);

    // ==== overlap region: only old-slot / pure-input reads ====
    if (t >= 2 && half == 1 && idx < 64 && wid == 0){   // y(t-2): 64 WGs x 1 batch
      int sy = t - 2;
      int yb = idx;
      unsigned a4[4], b4[4];
      ld_ring16_u(r1h + (t&1)*16384 + yb*256 + lane*4, a4);
      ld_ring16_u(r1l + (t&1)*16384 + yb*256 + lane*4, b4);
      float p = 0.f;
      #pragma unroll
      for (int j=0;j<4;j++){
        unsigned qa=a4[j], qb=b4[j];
        float e0 = __uint_as_float(qa<<16) + __uint_as_float(qb<<16);
        float e1 = __uint_as_float(qa & 0xFFFF0000u) + __uint_as_float(qb & 0xFFFF0000u);
        p += e0*wl[2*j] + e1*wl[2*j+1];
      }
      #pragma unroll
      for (int m=1; m<64; m<<=1) p += __shfl_xor(p, m, 64);
      if (lane == 0) st_agent_f(&out[yb*512 + sy], p + blin_r);
    }
    if (half == 0 && t+1 < TT){          // stage x(t+1) into LDS buf (t+1)&1
      int m = tid>>3, dd = (tid&7)*16;
      const float* xp = x + ((size_t)(bgrp*32+m))*65536 + (size_t)(t+1)*128 + dd;
      float4 v0 = *(const float4*)xp,      v1 = *(const float4*)(xp+4),
             v2 = *(const float4*)(xp+8),  v3 = *(const float4*)(xp+12);
      float vv[16] = {v0.x,v0.y,v0.z,v0.w, v1.x,v1.y,v1.z,v1.w,
                      v2.x,v2.y,v2.z,v2.w, v3.x,v3.y,v3.z,v3.w};
      unsigned uh[8], ul[8];
      #pragma unroll
      for (int j=0;j<8;j++){
        unsigned short hA = f2bf(vv[2*j]),   hB = f2bf(vv[2*j+1]);
        unsigned short lA = f2bf(vv[2*j]-bf2f(hA)), lB = f2bf(vv[2*j+1]-bf2f(hB));
        uh[j] = (unsigned)hA | ((unsigned)hB<<16);
        ul[j] = (unsigned)lA | ((unsigned)lB<<16);
      }
      unsigned* dh = xsh_s + ((t+1)&1)*2176 + m*68 + (dd>>1);
      unsigned* dl = xsl_s + ((t+1)&1)*2176 + m*68 + (dd>>1);
      *(uint4*)dh     = make_uint4(uh[0],uh[1],uh[2],uh[3]);
      *(uint4*)(dh+4) = make_uint4(uh[4],uh[5],uh[6],uh[7]);
      *(uint4*)dl     = make_uint4(ul[0],ul[1],ul[2],ul[3]);
      *(uint4*)(dl+4) = make_uint4(ul[4],ul[5],ul[6],ul[7]);
    }
    // ==== end overlap ====

    gb_wait(flags, rel, wg, tid, phase);
    ++phase;
  }
}

extern "C" void kernel_launch(void* const* d_in, const int* in_sizes, int n_in,
                              void* d_out, int out_size, void* d_ws, size_t ws_size,
                              hipStream_t stream)
{
  (void)in_sizes; (void)n_in; (void)out_size; (void)ws_size;
  const float* x    = (const float*)d_in[0];
  const float* h0   = (const float*)d_in[1];
  const float* c0   = (const float*)d_in[2];
  const float* wih0 = (const float*)d_in[3];
  const float* whh0 = (const float*)d_in[4];
  const float* bih0 = (const float*)d_in[5];
  const float* bhh0 = (const float*)d_in[6];
  const float* wih1 = (const float*)d_in[7];
  const float* whh1 = (const float*)d_in[8];
  const float* bih1 = (const float*)d_in[9];
  const float* bhh1 = (const float*)d_in[10];
  const float* wlin = (const float*)d_in[11];
  const float* blin = (const float*)d_in[12];
  float* outp = (float*)d_out;
  float* wsp  = (float*)d_ws;

  // zero flags (16KB) + release lines (2KB); rings fully rewritten by the kernel
  hipMemsetAsync(d_ws, 0, 18432, stream);

  void* args[] = { &x, &h0, &c0, &wih0, &whh0, &bih0, &bhh0,
                   &wih1, &whh1, &bih1, &bhh1, &wlin, &blin, &outp, &wsp };
  hipError_t err = hipLaunchCooperativeKernel((const void*)lstm_pers,
                                              dim3(NWG), dim3(256), args, 0, stream);
  if (err != hipSuccess){
    // Fallback: 1 block/CU (140KB LDS), 256 blocks on 256 CUs -> co-resident.
    hipLaunchKernelGGL(lstm_pers, dim3(NWG), dim3(256), 0, stream,
                       x, h0, c0, wih0, whh0, bih0, bhh0,
                       wih1, whh1, bih1, bhh1, wlin, blin, outp, wsp);
  }
}

// Round 11
// 8322.369 us; speedup vs baseline: 1.0294x; 1.0075x over previous
//
#include <hip/hip_runtime.h>
#include <math.h>

// Persistent cooperative 2-layer LSTM. Round 11: decoupled dataflow domains.
// B=64, T=512, D=128, H=512. 256 WGs x 256 threads (4 waves), 1 block/CU.
// WG w: bgrp = w&1, half = (w>>1)&1 (layer), cg = w>>2 (8 h-cols).
// 4 independent groups of 64 WGs: (bgrp, layer). No global barrier:
//  - each group: single-hop direct all-poll over its own 64 per-WG flag lines
//    (lane l polls flag l; no aggregator, no release hop).
//  - L1 group additionally polls its L0 group's flags (h0(s) ready <=> F0>=s+2).
//  - L0 runs ahead of L1 (ring0 depth 4) with backpressure F1 >= t-2
//    (<=> L1 completed step t-4, the last consumer of the slot being reused).
// Flag value = 1 + steps completed (memset 0; =1 after ring init).
// Ring slot for h(j) = (j+1)&3. All ring writes: 32-bit relaxed agent stores
// (proven); all ring reads: 64-bit relaxed agent atomic loads (proven, R10).
// Split precision MFMA: gates = Whi*hhi + Whi*hlo + Wlo*hhi (fp32 acc, ~2^-17).
//
// ws layout (bytes): flags[4][64] lines @0 (16KB); uints @20480:
//   r0h[4][64][256], r0l, r1h, r1l (256KB each plane, 1MB total).

#define TT 512
#define NWG 256

typedef __attribute__((ext_vector_type(8))) short short8;
typedef __attribute__((ext_vector_type(4))) float f32x4;

// red[khalf][m 0..31][n 0..31 pad 35]
#define RED(K,M,N) ((((K)*32+(M))*35)+(N))
#define RED_TOT (2*32*35)

__device__ __forceinline__ float fsigmoid(float v){ return 1.f/(1.f+__expf(-v)); }
__device__ __forceinline__ float ftanh(float v){ return 2.f/(1.f+__expf(-2.f*v)) - 1.f; }

__device__ __forceinline__ unsigned short f2bf(float f){
  unsigned u = __float_as_uint(f);
  unsigned r = ((u>>16)&1u) + 0x7FFFu;
  return (unsigned short)((u + r)>>16);
}
__device__ __forceinline__ float bf2f(unsigned short s){
  return __uint_as_float(((unsigned)s)<<16);
}
__device__ __forceinline__ void cvt8(const float4& a, const float4& b,
                                     short8& hi, short8& lo){
  float v[8] = {a.x,a.y,a.z,a.w,b.x,b.y,b.z,b.w};
  #pragma unroll
  for (int i=0;i<8;i++){
    unsigned short h = f2bf(v[i]);
    unsigned short l = f2bf(v[i] - bf2f(h));
    ((unsigned short*)&hi)[i] = h;
    ((unsigned short*)&lo)[i] = l;
  }
}

__device__ __forceinline__ void st_agent_f(float* p, float v){
  __hip_atomic_store(p, v, __ATOMIC_RELAXED, __HIP_MEMORY_SCOPE_AGENT);
}
__device__ __forceinline__ void st_agent_u32(unsigned* p, unsigned v){
  __hip_atomic_store(p, v, __ATOMIC_RELAXED, __HIP_MEMORY_SCOPE_AGENT);
}
__device__ __forceinline__ unsigned ldflag(const unsigned* p){
  return __hip_atomic_load(p, __ATOMIC_RELAXED, __HIP_MEMORY_SCOPE_AGENT);
}

// Coherent 16B ring read: two 64-bit relaxed agent atomic loads (proven R10).
__device__ __forceinline__ short8 ld_ring16(const unsigned* p){
  const unsigned long long* q = (const unsigned long long*)p;
  union { unsigned long long u[2]; short8 s; } v;
  v.u[0] = __hip_atomic_load(&q[0], __ATOMIC_RELAXED, __HIP_MEMORY_SCOPE_AGENT);
  v.u[1] = __hip_atomic_load(&q[1], __ATOMIC_RELAXED, __HIP_MEMORY_SCOPE_AGENT);
  return v.s;
}
__device__ __forceinline__ void ld_ring16_u(const unsigned* p, unsigned o[4]){
  const unsigned long long* q = (const unsigned long long*)p;
  unsigned long long a = __hip_atomic_load(&q[0], __ATOMIC_RELAXED, __HIP_MEMORY_SCOPE_AGENT);
  unsigned long long b = __hip_atomic_load(&q[1], __ATOMIC_RELAXED, __HIP_MEMORY_SCOPE_AGENT);
  o[0] = (unsigned)a; o[1] = (unsigned)(a>>32);
  o[2] = (unsigned)b; o[3] = (unsigned)(b>>32);
}

// Gate MFMA loop; ring A-frags via agent atomic loads, x via LDS stage.
template<int KFC, int LAYER, int KHALF>
__device__ __forceinline__ void gates_mfma(
    const unsigned* __restrict__ rAh, const unsigned* __restrict__ rAl,
    const unsigned* __restrict__ rBh, const unsigned* __restrict__ rBl,
    const unsigned* xsh_t, const unsigned* xsl_t,
    const unsigned short* wh, const unsigned short* wlo,
    int m0, int m1, int kslot, int nidx,
    f32x4& acc0, f32x4& acc1)
{
  constexpr int KB = LAYER ? (KHALF*512) : (KHALF*320);
  #pragma unroll
  for (int kf=0; kf<KFC; ++kf){
    short8 a0h,a0l,a1h,a1l;
    if (LAYER==0 && KHALF==1 && kf>=6){
      int d2 = (kf-6)*16 + kslot*4;          // uint offset within x row
      a0h = *(const short8*)(xsh_t + (m0&31)*68 + d2);
      a0l = *(const short8*)(xsl_t + (m0&31)*68 + d2);
      a1h = *(const short8*)(xsh_t + (m1&31)*68 + d2);
      a1l = *(const short8*)(xsl_t + (m1&31)*68 + d2);
    } else {
      int kk = KB + kf*32 + kslot*8;
      const unsigned *bh, *bl; int k2;
      if (LAYER==1 && KHALF==1){ bh = rBh; bl = rBl; k2 = (kk-512)>>1; }
      else                     { bh = rAh; bl = rAl; k2 = kk>>1;       }
      a0h = ld_ring16(bh + m0*256 + k2);
      a0l = ld_ring16(bl + m0*256 + k2);
      a1h = ld_ring16(bh + m1*256 + k2);
      a1l = ld_ring16(bl + m1*256 + k2);
    }
    int c = ((KHALF*KFC + kf)*4 + kslot)*32 + nidx;
    short8 bhW = *(const short8*)(wh  + (size_t)c*8);
    short8 blW = *(const short8*)(wlo + (size_t)c*8);
    acc0 = __builtin_amdgcn_mfma_f32_16x16x32_bf16(a0h, bhW, acc0, 0,0,0);
    acc0 = __builtin_amdgcn_mfma_f32_16x16x32_bf16(a0l, bhW, acc0, 0,0,0);
    acc0 = __builtin_amdgcn_mfma_f32_16x16x32_bf16(a0h, blW, acc0, 0,0,0);
    acc1 = __builtin_amdgcn_mfma_f32_16x16x32_bf16(a1h, bhW, acc1, 0,0,0);
    acc1 = __builtin_amdgcn_mfma_f32_16x16x32_bf16(a1l, bhW, acc1, 0,0,0);
    acc1 = __builtin_amdgcn_mfma_f32_16x16x32_bf16(a1h, blW, acc1, 0,0,0);
  }
}

__global__ __launch_bounds__(256, 1) void lstm_pers(
    const float* __restrict__ x,    const float* __restrict__ h0in, const float* __restrict__ c0in,
    const float* __restrict__ wih0, const float* __restrict__ whh0,
    const float* __restrict__ bih0, const float* __restrict__ bhh0,
    const float* __restrict__ wih1, const float* __restrict__ whh1,
    const float* __restrict__ bih1, const float* __restrict__ bhh1,
    const float* __restrict__ wlin, const float* __restrict__ blin,
    float* __restrict__ out, float* ws)
{
  __shared__ __align__(16) unsigned short wlds_hi[32768];   // 65,536 B
  __shared__ __align__(16) unsigned short wlds_lo[32768];   // 65,536 B
  __shared__ __align__(16) float red[RED_TOT];              //  8,960 B
  const int tid = threadIdx.x, wg = blockIdx.x;
  const int lane = tid & 63;
  const int wid  = tid >> 6;
  const int bgrp = wg & 1;
  const int half = (wg >> 1) & 1;      // 0: layer0, 1: layer1
  const int cg   = wg >> 2;            // 0..63
  const int colbase = cg*8;
  const int khalf = wid & 1;
  const int ntile = wid >> 1;

  unsigned* flags = (unsigned*)ws;                  // 4 domains x 64 lines
  unsigned* F0 = flags + (bgrp*2 + 0)*64*16;        // this bgrp's L0 flags
  unsigned* F1 = flags + (bgrp*2 + 1)*64*16;        // this bgrp's L1 flags
  unsigned* myF = half ? F1 : F0;
  unsigned* r0h = ((unsigned*)ws) + 5120;           // [4][64][256] each plane
  unsigned* r0l = r0h + 65536;
  unsigned* r1h = r0h + 131072;
  unsigned* r1l = r0h + 196608;

  unsigned* xsh_s = (unsigned*)(wlds_hi + 20480);   // L0 WGs only (overlay)
  unsigned* xsl_s = (unsigned*)(wlds_lo + 20480);

  // ---- W (bf16 hi/lo) into LDS, once. chunk c = ((kh*KFC+kf)*4+ks)*32+n ----
  if (half == 0){
    for (int c = tid; c < 2560; c += 256){
      int kh = c / 1280; int rem = c - kh*1280;
      int kf = rem >> 7; int rem2 = rem & 127;
      int ks = rem2 >> 5; int n = rem2 & 31;
      int kk = kh*320 + kf*32 + ks*8;
      int wrow = (n>>3)*512 + colbase + (n&7);
      const float* src; long off;
      if (kk < 512){ src = whh0; off = (long)wrow*512 + kk; }
      else         { src = wih0; off = (long)wrow*128 + (kk-512); }
      float4 a = *(const float4*)(src + off);
      float4 b = *(const float4*)(src + off + 4);
      short8 hi, lo; cvt8(a, b, hi, lo);
      *(short8*)(wlds_hi + (size_t)c*8) = hi;
      *(short8*)(wlds_lo + (size_t)c*8) = lo;
    }
  } else {
    for (int c = tid; c < 4096; c += 256){
      int kh = c >> 11; int rem = c & 2047;
      int kf = rem >> 7; int rem2 = rem & 127;
      int ks = rem2 >> 5; int n = rem2 & 31;
      int kk = kh*512 + kf*32 + ks*8;
      int wrow = (n>>3)*512 + colbase + (n&7);
      const float* src; long off;
      if (kk < 512){ src = whh1; off = (long)wrow*512 + kk; }
      else         { src = wih1; off = (long)wrow*512 + (kk-512); }
      float4 a = *(const float4*)(src + off);
      float4 b = *(const float4*)(src + off + 4);
      short8 hi, lo; cvt8(a, b, hi, lo);
      *(short8*)(wlds_hi + (size_t)c*8) = hi;
      *(short8*)(wlds_lo + (size_t)c*8) = lo;
    }
  }

  // ---- activation-role state: 1 cell/thread, this WG's layer ----
  const int m_l = tid >> 3;            // 0..31 local batch
  const int cl  = tid & 7;             // 0..7 local col
  const int col_own = colbase + cl;
  const int bb_a = bgrp*32 + m_l;
  float biasr[4], cst;
  #pragma unroll
  for (int g=0; g<4; ++g){
    biasr[g] = half ? (bih1[g*512+col_own] + bhh1[g*512+col_own])
                    : (bih0[g*512+col_own] + bhh0[g*512+col_own]);
  }
  cst = c0in[half*32768 + bb_a*512 + col_own];
  float blin_r = blin[0];

  // ---- y-role state: lane holds wlin[8k..8k+8) ----
  float wl[8];
  {
    const float4* wp = (const float4*)wlin + (lane*2);
    float4 w0 = wp[0], w1 = wp[1];
    wl[0]=w0.x; wl[1]=w0.y; wl[2]=w0.z; wl[3]=w0.w;
    wl[4]=w1.x; wl[5]=w1.y; wl[6]=w1.z; wl[7]=w1.w;
  }

  // ---- init h(-1) into ring slot 0, DOMAIN-RESTRICTED (own bgrp+layer) ----
  {
    int e = cg*256 + tid;                  // [0, 16384) within (half,bgrp) slab
    if (!(e & 1)){
      int m = e >> 9;                      // 0..31 local batch
      int col = e & 511;
      const float* src = h0in + half*32768 + (size_t)(bgrp*32+m)*512 + col;
      float v0 = src[0], v1 = src[1];
      unsigned short hA = f2bf(v0), lA = f2bf(v0 - bf2f(hA));
      unsigned short hB = f2bf(v1), lB = f2bf(v1 - bf2f(hB));
      unsigned uh = (unsigned)hA | ((unsigned)hB<<16);
      unsigned ul = (unsigned)lA | ((unsigned)lB<<16);
      int idx2 = (bgrp*32+m)*256 + (col>>1);     // slot 0
      unsigned* ph = half ? r1h : r0h;
      unsigned* pl = half ? r1l : r0l;
      st_agent_u32(ph + idx2, uh);
      st_agent_u32(pl + idx2, ul);
    }
  }

  // ---- x stage for t=0 (L0 WGs, LDS-local) ----
  if (half == 0){
    int m = tid>>3, dd = (tid&7)*16;
    const float* xp = x + ((size_t)(bgrp*32+m))*65536 + 0*128 + dd;
    float4 v0 = *(const float4*)xp,      v1 = *(const float4*)(xp+4),
           v2 = *(const float4*)(xp+8),  v3 = *(const float4*)(xp+12);
    float vv[16] = {v0.x,v0.y,v0.z,v0.w, v1.x,v1.y,v1.z,v1.w,
                    v2.x,v2.y,v2.z,v2.w, v3.x,v3.y,v3.z,v3.w};
    unsigned uh[8], ul[8];
    #pragma unroll
    for (int j=0;j<8;j++){
      unsigned short hA = f2bf(vv[2*j]),   hB = f2bf(vv[2*j+1]);
      unsigned short lA = f2bf(vv[2*j]-bf2f(hA)), lB = f2bf(vv[2*j+1]-bf2f(hB));
      uh[j] = (unsigned)hA | ((unsigned)hB<<16);
      ul[j] = (unsigned)lA | ((unsigned)lB<<16);
    }
    unsigned* dh = xsh_s + m*68 + (dd>>1);
    unsigned* dl = xsl_s + m*68 + (dd>>1);
    *(uint4*)dh     = make_uint4(uh[0],uh[1],uh[2],uh[3]);
    *(uint4*)(dh+4) = make_uint4(uh[4],uh[5],uh[6],uh[7]);
    *(uint4*)dl     = make_uint4(ul[0],ul[1],ul[2],ul[3]);
    *(uint4*)(dl+4) = make_uint4(ul[4],ul[5],ul[6],ul[7]);
  }

  // publish init: flag = 1
  asm volatile("s_waitcnt vmcnt(0)" ::: "memory");
  __syncthreads();
  if (tid == 0) st_agent_u32(&myF[cg*16], 1u);

  const int m0 = bgrp*32 + (lane & 15);
  const int m1 = m0 + 16;
  const int kslot = lane >> 4;
  const int nidx  = ntile*16 + (lane & 15);

  if (half == 0){
    // ================= LAYER-0 GROUP: 512 dense steps =================
    for (int t = 0; t < TT; ++t){
      // poll: own h0(t-1) ready (F0>=t+1); backpressure F1>=t-2 (t>=4):
      // slot (t+1)&3 holds h0(t-4), last consumed by L1 step t-4 (flag t-2).
      if (tid < 64){
        const unsigned need0 = (unsigned)(t+1);
        const bool bp = (t >= 4);
        const unsigned need1 = (unsigned)(t-2);
        for(;;){
          bool ok = ldflag(&F0[tid*16]) >= need0;
          if (bp) ok &= (ldflag(&F1[tid*16]) >= need1);
          if (__all(ok)) break;
          __builtin_amdgcn_s_sleep(2);
        }
      }
      __syncthreads();

      const unsigned* rAh = r0h + (t&3)*16384;       // h0(t-1)
      const unsigned* rAl = r0l + (t&3)*16384;
      const unsigned* xsh_t = xsh_s + (t&1)*2176;
      const unsigned* xsl_t = xsl_s + (t&1)*2176;
      f32x4 acc0 = {0.f,0.f,0.f,0.f}, acc1 = {0.f,0.f,0.f,0.f};
      if (khalf == 0) gates_mfma<10,0,0>(rAh,rAl,0,0,xsh_t,xsl_t,wlds_hi,wlds_lo,m0,m1,kslot,nidx,acc0,acc1);
      else            gates_mfma<10,0,1>(rAh,rAl,0,0,xsh_t,xsl_t,wlds_hi,wlds_lo,m0,m1,kslot,nidx,acc0,acc1);
      #pragma unroll
      for (int r=0; r<4; ++r){
        int mm = kslot*4 + r;
        red[RED(khalf, mm,    nidx)] = acc0[r];
        red[RED(khalf, 16+mm, nidx)] = acc1[r];
      }
      __syncthreads();

      // activation -> h0(t) into slot (t+1)&3
      {
        float g4[4];
        #pragma unroll
        for (int g=0; g<4; ++g){
          int n = g*8 + cl;
          g4[g] = red[RED(0,m_l,n)] + red[RED(1,m_l,n)] + biasr[g];
        }
        float gi = fsigmoid(g4[0]);
        float gf = fsigmoid(g4[1]);
        float gg = ftanh   (g4[2]);
        float go = fsigmoid(g4[3]);
        float c = gf*cst + gi*gg;
        cst = c;
        float h = go * ftanh(c);
        float h_oth = __shfl_xor(h, 1, 64);
        if (!(tid & 1)){
          unsigned short hA = f2bf(h),     lA = f2bf(h - bf2f(hA));
          unsigned short hB = f2bf(h_oth), lB = f2bf(h_oth - bf2f(hB));
          unsigned uh = (unsigned)hA | ((unsigned)hB<<16);
          unsigned ul = (unsigned)lA | ((unsigned)lB<<16);
          int off = ((t+1)&3)*16384 + bb_a*256 + (col_own>>1);
          st_agent_u32(r0h + off, uh);
          st_agent_u32(r0l + off, ul);
        }
      }
      asm volatile("s_waitcnt vmcnt(0)" ::: "memory");
      __syncthreads();
      if (tid == 0) st_agent_u32(&F0[cg*16], (unsigned)(t+2));

      // stage x(t+1) (LDS-local; ordered vs next read by next poll's sync)
      if (t+1 < TT){
        int m = tid>>3, dd = (tid&7)*16;
        const float* xp = x + ((size_t)(bgrp*32+m))*65536 + (size_t)(t+1)*128 + dd;
        float4 v0 = *(const float4*)xp,      v1 = *(const float4*)(xp+4),
               v2 = *(const float4*)(xp+8),  v3 = *(const float4*)(xp+12);
        float vv[16] = {v0.x,v0.y,v0.z,v0.w, v1.x,v1.y,v1.z,v1.w,
                        v2.x,v2.y,v2.z,v2.w, v3.x,v3.y,v3.z,v3.w};
        unsigned uh[8], ul[8];
        #pragma unroll
        for (int j=0;j<8;j++){
          unsigned short hA = f2bf(vv[2*j]),   hB = f2bf(vv[2*j+1]);
          unsigned short lA = f2bf(vv[2*j]-bf2f(hA)), lB = f2bf(vv[2*j+1]-bf2f(hB));
          uh[j] = (unsigned)hA | ((unsigned)hB<<16);
          ul[j] = (unsigned)lA | ((unsigned)lB<<16);
        }
        unsigned* dh = xsh_s + ((t+1)&1)*2176 + m*68 + (dd>>1);
        unsigned* dl = xsl_s + ((t+1)&1)*2176 + m*68 + (dd>>1);
        *(uint4*)dh     = make_uint4(uh[0],uh[1],uh[2],uh[3]);
        *(uint4*)(dh+4) = make_uint4(uh[4],uh[5],uh[6],uh[7]);
        *(uint4*)dl     = make_uint4(ul[0],ul[1],ul[2],ul[3]);
        *(uint4*)(dl+4) = make_uint4(ul[4],ul[5],ul[6],ul[7]);
      }
    }
  } else {
    // ================= LAYER-1 GROUP: 512 dense steps =================
    for (int s = 0; s < TT; ++s){
      // poll: own h1(s-1) (F1>=s+1) AND h0(s) from L0 (F0>=s+2).
      if (tid < 64){
        const unsigned need1 = (unsigned)(s+1);
        const unsigned need0 = (unsigned)(s+2);
        for(;;){
          bool ok = (ldflag(&F1[tid*16]) >= need1)
                  & (ldflag(&F0[tid*16]) >= need0);
          if (__all(ok)) break;
          __builtin_amdgcn_s_sleep(2);
        }
      }
      __syncthreads();

      // y(s-2): h1(s-2) fully visible (F1>=s+1 > s-1). Slot (s-1)&3.
      if (s >= 2 && cg < 32 && wid == 0){
        int j = s - 2;
        int yb = bgrp*32 + cg;
        unsigned a4[4], b4[4];
        ld_ring16_u(r1h + ((s-1)&3)*16384 + yb*256 + lane*4, a4);
        ld_ring16_u(r1l + ((s-1)&3)*16384 + yb*256 + lane*4, b4);
        float p = 0.f;
        #pragma unroll
        for (int q=0;q<4;q++){
          unsigned qa=a4[q], qb=b4[q];
          float e0 = __uint_as_float(qa<<16) + __uint_as_float(qb<<16);
          float e1 = __uint_as_float(qa & 0xFFFF0000u) + __uint_as_float(qb & 0xFFFF0000u);
          p += e0*wl[2*q] + e1*wl[2*q+1];
        }
        #pragma unroll
        for (int m=1; m<64; m<<=1) p += __shfl_xor(p, m, 64);
        if (lane == 0) st_agent_f(&out[yb*512 + j], p + blin_r);
      }

      const unsigned* rAh = r1h + (s&3)*16384;       // h1(s-1)
      const unsigned* rAl = r1l + (s&3)*16384;
      const unsigned* rBh = r0h + ((s+1)&3)*16384;   // h0(s)
      const unsigned* rBl = r0l + ((s+1)&3)*16384;
      f32x4 acc0 = {0.f,0.f,0.f,0.f}, acc1 = {0.f,0.f,0.f,0.f};
      if (khalf == 0) gates_mfma<16,1,0>(rAh,rAl,rBh,rBl,0,0,wlds_hi,wlds_lo,m0,m1,kslot,nidx,acc0,acc1);
      else            gates_mfma<16,1,1>(rAh,rAl,rBh,rBl,0,0,wlds_hi,wlds_lo,m0,m1,kslot,nidx,acc0,acc1);
      #pragma unroll
      for (int r=0; r<4; ++r){
        int mm = kslot*4 + r;
        red[RED(khalf, mm,    nidx)] = acc0[r];
        red[RED(khalf, 16+mm, nidx)] = acc1[r];
      }
      __syncthreads();

      // activation -> h1(s) into slot (s+1)&3
      {
        float g4[4];
        #pragma unroll
        for (int g=0; g<4; ++g){
          int n = g*8 + cl;
          g4[g] = red[RED(0,m_l,n)] + red[RED(1,m_l,n)] + biasr[g];
        }
        float gi = fsigmoid(g4[0]);
        float gf = fsigmoid(g4[1]);
        float gg = ftanh   (g4[2]);
        float go = fsigmoid(g4[3]);
        float c = gf*cst + gi*gg;
        cst = c;
        float h = go * ftanh(c);
        float h_oth = __shfl_xor(h, 1, 64);
        if (!(tid & 1)){
          unsigned short hA = f2bf(h),     lA = f2bf(h - bf2f(hA));
          unsigned short hB = f2bf(h_oth), lB = f2bf(h_oth - bf2f(hB));
          unsigned uh = (unsigned)hA | ((unsigned)hB<<16);
          unsigned ul = (unsigned)lA | ((unsigned)lB<<16);
          int off = ((s+1)&3)*16384 + bb_a*256 + (col_own>>1);
          st_agent_u32(r1h + off, uh);
          st_agent_u32(r1l + off, ul);
        }
      }
      asm volatile("s_waitcnt vmcnt(0)" ::: "memory");
      __syncthreads();
      if (tid == 0) st_agent_u32(&F1[cg*16], (unsigned)(s+2));
    }

    // epilogue: wait for all h1(511), then y(510), y(511)
    if (tid < 64){
      const unsigned need = (unsigned)(TT+1);
      while (ldflag(&F1[tid*16]) < need) __builtin_amdgcn_s_sleep(2);
    }
    __syncthreads();
    if (cg < 32 && wid == 0){
      #pragma unroll
      for (int e=0; e<2; ++e){
        int j = TT-2+e;                       // 510, 511
        int yb = bgrp*32 + cg;
        unsigned a4[4], b4[4];
        ld_ring16_u(r1h + ((j+1)&3)*16384 + yb*256 + lane*4, a4);
        ld_ring16_u(r1l + ((j+1)&3)*16384 + yb*256 + lane*4, b4);
        float p = 0.f;
        #pragma unroll
        for (int q=0;q<4;q++){
          unsigned qa=a4[q], qb=b4[q];
          float e0 = __uint_as_float(qa<<16) + __uint_as_float(qb<<16);
          float e1 = __uint_as_float(qa & 0xFFFF0000u) + __uint_as_float(qb & 0xFFFF0000u);
          p += e0*wl[2*q] + e1*wl[2*q+1];
        }
        #pragma unroll
        for (int m=1; m<64; m<<=1) p += __shfl_xor(p, m, 64);
        if (lane == 0) st_agent_f(&out[yb*512 + j], p + blin_r);
      }
    }
  }
}

extern "C" void kernel_launch(void* const* d_in, const int* in_sizes, int n_in,
                              void* d_out, int out_size, void* d_ws, size_t ws_size,
                              hipStream_t stream)
{
  (void)in_sizes; (void)n_in; (void)out_size; (void)ws_size;
  const float* x    = (const float*)d_in[0];
  const float* h0   = (const float*)d_in[1];
  const float* c0   = (const float*)d_in[2];
  const float* wih0 = (const float*)d_in[3];
  const float* whh0 = (const float*)d_in[4];
  const float* bih0 = (const float*)d_in[5];
  const float* bhh0 = (const float*)d_in[6];
  const float* wih1 = (const float*)d_in[7];
  const float* whh1 = (const float*)d_in[8];
  const float* bih1 = (const float*)d_in[9];
  const float* bhh1 = (const float*)d_in[10];
  const float* wlin = (const float*)d_in[11];
  const float* blin = (const float*)d_in[12];
  float* outp = (float*)d_out;
  float* wsp  = (float*)d_ws;

  // zero flag lines; rings fully rewritten by the kernel each launch
  hipMemsetAsync(d_ws, 0, 18432, stream);

  void* args[] = { &x, &h0, &c0, &wih0, &whh0, &bih0, &bhh0,
                   &wih1, &whh1, &bih1, &bhh1, &wlin, &blin, &outp, &wsp };
  hipError_t err = hipLaunchCooperativeKernel((const void*)lstm_pers,
                                              dim3(NWG), dim3(256), args, 0, stream);
  if (err != hipSuccess){
    // Fallback: 1 block/CU (140KB LDS), 256 blocks on 256 CUs -> co-resident.
    hipLaunchKernelGGL(lstm_pers, dim3(NWG), dim3(256), 0, stream,
                       x, h0, c0, wih0, whh0, bih0, bhh0,
                       wih1, whh1, bih1, bhh1, wlin, blin, outp, wsp);
  }
}